// Round 17
// baseline (617.890 us; speedup 1.0000x reference)
//
#include <hip/hip_runtime.h>

typedef unsigned short u16;
typedef unsigned int u32;
typedef __attribute__((ext_vector_type(4))) float f32x4;
typedef __attribute__((ext_vector_type(8))) __bf16 bf16x8;
typedef __attribute__((ext_vector_type(4))) unsigned int u32x4;
typedef __attribute__((ext_vector_type(2))) unsigned int u32x2;

#define DEV static __device__ __forceinline__

// ---------------- problem constants ----------------
#define NNODE 4096
#define DMODEL 768
#define NEDGE 131072

// ---------------- static workspace ----------------
static constexpr size_t OFF_X     = 0;           // f32 [4096][768]
static constexpr size_t OFF_X2    = 12582912;    // f32 [4096][768] pre-LN
static constexpr size_t OFF_AMSG  = 25165824;    // bf16 [4096][768]
static constexpr size_t OFF_AUPD  = 31457280;    // bf16 [4096][1536] = [xh, aggh]
static constexpr size_t OFF_WMSG  = 44040192;    // bf16 [3][5][768][768]
static constexpr size_t OFF_WUPD  = 61734912;    // bf16 [3][768][1536]
static constexpr size_t OFF_WIP   = 68812800;    // bf16 [2304][768]
static constexpr size_t OFF_WOP   = 72351744;    // bf16 [768][768]
static constexpr size_t OFF_Q     = 73531392;    // bf16 [8][4096][96] (pre-scaled)
static constexpr size_t OFF_K     = 79822848;    // bf16 [8][4096][96]
static constexpr size_t OFF_V     = 86114304;    // bf16 [8][96][4096] (transposed)
static constexpr size_t OFF_CTX   = 92405760;    // bf16 [4096][768]
static constexpr size_t OFF_STATS = 98697216;    // f32 [2][8][4096] (m, invl)
static constexpr size_t OFF_ML    = 98959360;    // f32 [2][4][8][4096] (m,l partials)
static constexpr size_t OFF_DEG   = 100007936;   // int [4096]
static constexpr size_t OFF_OFFS  = 100024320;   // int [4097]
static constexpr size_t OFF_CUR   = 100040960;   // int [4096]
static constexpr size_t OFF_PACK  = 100057344;   // int [131072] src | etype<<12
static constexpr size_t OFF_PART  = 100581632;   // f32 [256][768]
static constexpr size_t OFF_POOL  = 101368064;   // f32 [768]
static constexpr size_t OFF_H1    = 101371136;   // f32 [512]
static constexpr size_t OFF_H2    = 101373184;   // f32 [256]
static constexpr size_t OFF_Y     = 101374208;   // bf16 [5][4096][768] (8B-aligned)
static constexpr size_t WS_TOTAL  = 132831488;

__device__ __attribute__((aligned(256))) unsigned char g_ws[WS_TOTAL];

// ---------------- helpers ----------------
DEV u16 f2bf(float f) {                       // native v_cvt (RTNE)
  return __builtin_bit_cast(u16, (__bf16)f);
}
DEV float bf2f(u16 h) {
  union { unsigned u; float f; } v; v.u = ((unsigned)h) << 16;
  return v.f;
}
DEV void gl_lds16(const void* g, void* l) {
  __builtin_amdgcn_global_load_lds((const __attribute__((address_space(1))) void*)g,
                                   (__attribute__((address_space(3))) void*)l, 16, 0, 0);
}
DEV f32x4 mfma16(bf16x8 a, bf16x8 b, f32x4 c) {
  return __builtin_amdgcn_mfma_f32_16x16x32_bf16(a, b, c, 0, 0, 0);
}
// bijective XCD swizzle: rank order (z, bm, bn), bn fastest.
// requires nwg % 8 == 0 (all call sites satisfy this).
DEV void xcd_swz(int& z, int& bmy, int& bnx) {
  const int gx = gridDim.x, gy = gridDim.y;
  const int nwg = gx * gy * gridDim.z;
  const int L = blockIdx.x + gx * (blockIdx.y + gy * blockIdx.z);
  const int R = (L & 7) * (nwg >> 3) + (L >> 3);
  const int gxy = gx * gy;
  z = R / gxy;
  const int rem = R - z * gxy;
  bmy = rem / gx;
  bnx = rem - bmy * gx;
}

// ---------------- CSR build ----------------
__global__ void zero_kernel(int* p, int n) {
  int i = blockIdx.x * 256 + threadIdx.x;
  if (i < n) p[i] = 0;
}
__global__ void deg_kernel(const int* __restrict__ ei, int* __restrict__ deg) {
  int e = blockIdx.x * 256 + threadIdx.x;
  atomicAdd(&deg[ei[NEDGE + e]], 1);
}
__global__ void scan_kernel(const int* __restrict__ deg, int* __restrict__ offs, int* __restrict__ cur) {
  __shared__ int buf[1024];
  int t = threadIdx.x;
  int v0 = deg[t*4], v1 = deg[t*4+1], v2 = deg[t*4+2], v3 = deg[t*4+3];
  int s = v0 + v1 + v2 + v3;
  buf[t] = s;
  __syncthreads();
  for (int off = 1; off < 1024; off <<= 1) {
    int add = (t >= off) ? buf[t - off] : 0;
    __syncthreads();
    buf[t] += add;
    __syncthreads();
  }
  int run = buf[t] - s;
  offs[t*4] = run; cur[t*4] = run; run += v0;
  offs[t*4+1] = run; cur[t*4+1] = run; run += v1;
  offs[t*4+2] = run; cur[t*4+2] = run; run += v2;
  offs[t*4+3] = run; cur[t*4+3] = run; run += v3;
  if (t == 1023) offs[4096] = run;
}
__global__ void scatter_kernel(const int* __restrict__ ei, const int* __restrict__ ety,
                               int* __restrict__ cur, int* __restrict__ pack) {
  int e = blockIdx.x * 256 + threadIdx.x;
  int tg = ei[NEDGE + e];
  int pos = atomicAdd(&cur[tg], 1);
  pack[pos] = ei[e] | (ety[e] << 12);
}

// ---------------- weight conversion (vectorized: 4 elems/thread) ----------------
__global__ void convert_bf_kernel(const float* __restrict__ W, u16* __restrict__ out, int total4) {
  for (int i = blockIdx.x * 256 + threadIdx.x; i < total4; i += gridDim.x * 256) {
    f32x4 w = *(const f32x4*)(W + (size_t)i * 4);
    u32x2 o;
    o.x = (u32)f2bf(w.x) | ((u32)f2bf(w.y) << 16);
    o.y = (u32)f2bf(w.z) | ((u32)f2bf(w.w) << 16);
    *(u32x2*)(out + (size_t)i * 4) = o;
  }
}

// ---------------- embed + bf16 pack ----------------
__global__ void embed_kernel(const float* __restrict__ nf, const int* __restrict__ nty,
                             const float* __restrict__ se, const float* __restrict__ ce,
                             const float* __restrict__ ae,
                             float* __restrict__ x, u16* __restrict__ Amsg, u16* __restrict__ Aupd) {
  int v = blockIdx.x, t = threadIdx.x;
  int typ = nty[v];
  const float* tab = (typ == 0) ? se + (size_t)(v % 1000) * 768
                   : (typ == 1) ? ce + (size_t)(v % 5000) * 768
                                : ae + (size_t)(v % 2000) * 768;
  #pragma unroll
  for (int i = 0; i < 3; ++i) {
    int c = t + i * 256;
    float f = nf[(size_t)v * 768 + c] + tab[c];
    x[(size_t)v * 768 + c] = f;
    u16 hi = f2bf(f);
    Amsg[(size_t)v * 768 + c] = hi;
    Aupd[(size_t)v * 1536 + c] = hi;
  }
}

// ---------------- bt-GEMM 128x128: C[M,N] = A[M,K] * B[N,K]^T (XCD-swizzled) ----------------
// EPI 0: f32 C. EPI 1: relu+resid f32 C. EPI 2: qkv scatter. EPI 3: bf16 C (z-strided).
template<int EPI>
__global__ void __launch_bounds__(256, 3)
gemm_bt(const u16* __restrict__ A, int lda,
        const u16* __restrict__ B0, int ldb, int K,
        const float* __restrict__ bias0,
        float* __restrict__ C0, int ldc,
        const float* __restrict__ resid,
        u16* __restrict__ oq, u16* __restrict__ okk, u16* __restrict__ ov,
        long zsB, int zsBias, long zsC)
{
  __shared__ alignas(16) u16 sA[8192];  // [128][64] bf16, XOR-swizzled rows
  __shared__ alignas(16) u16 sB[8192];
  const int tid = threadIdx.x;
  const int lane = tid & 63, wid = tid >> 6;
  const int wr = wid >> 1, wc = wid & 1;
  const int li = lane & 15, g = lane >> 4;
  int z, bmy, bnx;
  xcd_swz(z, bmy, bnx);
  const int bm = bmy * 128, bn = bnx * 128;
  const u16* B = B0 + (size_t)z * zsB;
  const float* bias = bias0 + (size_t)z * zsBias;

  const int srow = tid >> 3;                       // 0..31
  const int scol = ((tid & 7) ^ (srow & 7)) * 8;   // pre-swizzled source col group
  const u16* Ag = A + (size_t)(bm + srow) * lda + scol;
  const u16* Bg = B + (size_t)(bn + srow) * ldb + scol;
  char* sAw = (char*)sA + wid * 1024;
  char* sBw = (char*)sB + wid * 1024;

  f32x4 acc[4][4];
  const f32x4 vz = {0.f, 0.f, 0.f, 0.f};
  #pragma unroll
  for (int i = 0; i < 4; ++i)
    #pragma unroll
    for (int j = 0; j < 4; ++j) acc[i][j] = vz;

  for (int k0 = 0; k0 < K; k0 += 64) {
    __syncthreads();
    #pragma unroll
    for (int is = 0; is < 4; ++is) {
      gl_lds16(Ag + (size_t)is * 32 * lda + k0, sAw + is * 4096);
      gl_lds16(Bg + (size_t)is * 32 * ldb + k0, sBw + is * 4096);
    }
    __syncthreads();
    #pragma unroll
    for (int kc = 0; kc < 2; ++kc) {
      bf16x8 av[4], bv[4];
      #pragma unroll
      for (int mt = 0; mt < 4; ++mt) {
        int row = wr * 64 + mt * 16 + li;
        av[mt] = *(const bf16x8*)((const char*)sA + row * 128 + ((kc * 64 + g * 16) ^ ((row & 7) << 4)));
      }
      #pragma unroll
      for (int nt = 0; nt < 4; ++nt) {
        int row = wc * 64 + nt * 16 + li;
        bv[nt] = *(const bf16x8*)((const char*)sB + row * 128 + ((kc * 64 + g * 16) ^ ((row & 7) << 4)));
      }
      #pragma unroll
      for (int mt = 0; mt < 4; ++mt)
        #pragma unroll
        for (int nt = 0; nt < 4; ++nt)
          acc[mt][nt] = mfma16(av[mt], bv[nt], acc[mt][nt]);
    }
  }
  // epilogue: C row = (lane>>4)*4+reg, col = lane&15
  #pragma unroll
  for (int mt = 0; mt < 4; ++mt) {
    #pragma unroll
    for (int nt = 0; nt < 4; ++nt) {
      #pragma unroll
      for (int r = 0; r < 4; ++r) {
        int gr = bm + wr * 64 + mt * 16 + g * 4 + r;
        int gc = bn + wc * 64 + nt * 16 + li;
        float v = acc[mt][nt][r] + bias[gc];
        if (EPI == 0) {
          C0[(size_t)z * zsC + (size_t)gr * ldc + gc] = v;
        } else if (EPI == 1) {
          C0[(size_t)gr * ldc + gc] = fmaxf(v, 0.f) + resid[(size_t)gr * 768 + gc];
        } else if (EPI == 3) {
          oq[(size_t)z * zsC + (size_t)gr * ldc + gc] = f2bf(v);
        } else {
          int part = gc / 768;
          int j = gc - part * 768;
          int h = j / 96, d = j - h * 96;
          if (part == 0)      oq[((size_t)(h << 12) + gr) * 96 + d] = f2bf(v * 0.10206207261596575f);
          else if (part == 1) okk[((size_t)(h << 12) + gr) * 96 + d] = f2bf(v);
          else                ov[((size_t)h * 96 + d) * 4096 + gr] = f2bf(v);
        }
      }
    }
  }
}

// ---------------- bt-GEMM 128x64 (narrow N; XCD-swizzled) ----------------
// EPI 0: f32 C. EPI 1: relu+resid f32 C.
template<int EPI>
__global__ void __launch_bounds__(256, 3)
gemm_bt64(const u16* __restrict__ A, int lda,
          const u16* __restrict__ B0, int ldb, int K,
          const float* __restrict__ bias,
          float* __restrict__ C0, int ldc,
          const float* __restrict__ resid)
{
  __shared__ alignas(16) u16 sA[8192];  // [128][64]
  __shared__ alignas(16) u16 sB[4096];  // [64][64]
  const int tid = threadIdx.x;
  const int lane = tid & 63, wid = tid >> 6;
  const int wr = wid >> 1, wc = wid & 1;
  const int li = lane & 15, g = lane >> 4;
  int z, bmy, bnx;
  xcd_swz(z, bmy, bnx);
  const int bm = bmy * 128, bn = bnx * 64;

  const int srow = tid >> 3;
  const int scol = ((tid & 7) ^ (srow & 7)) * 8;
  const u16* Ag = A + (size_t)(bm + srow) * lda + scol;
  const u16* Bg = B0 + (size_t)(bn + srow) * ldb + scol;
  char* sAw = (char*)sA + wid * 1024;
  char* sBw = (char*)sB + wid * 1024;

  f32x4 acc[4][2];
  const f32x4 vz = {0.f, 0.f, 0.f, 0.f};
  #pragma unroll
  for (int i = 0; i < 4; ++i) { acc[i][0] = vz; acc[i][1] = vz; }

  for (int k0 = 0; k0 < K; k0 += 64) {
    __syncthreads();
    #pragma unroll
    for (int is = 0; is < 4; ++is)
      gl_lds16(Ag + (size_t)is * 32 * lda + k0, sAw + is * 4096);
    #pragma unroll
    for (int is = 0; is < 2; ++is)
      gl_lds16(Bg + (size_t)is * 32 * ldb + k0, sBw + is * 4096);
    __syncthreads();
    #pragma unroll
    for (int kc = 0; kc < 2; ++kc) {
      bf16x8 av[4], bv[2];
      #pragma unroll
      for (int mt = 0; mt < 4; ++mt) {
        int row = wr * 64 + mt * 16 + li;
        av[mt] = *(const bf16x8*)((const char*)sA + row * 128 + ((kc * 64 + g * 16) ^ ((row & 7) << 4)));
      }
      #pragma unroll
      for (int nt = 0; nt < 2; ++nt) {
        int row = wc * 32 + nt * 16 + li;
        bv[nt] = *(const bf16x8*)((const char*)sB + row * 128 + ((kc * 64 + g * 16) ^ ((row & 7) << 4)));
      }
      #pragma unroll
      for (int mt = 0; mt < 4; ++mt)
        #pragma unroll
        for (int nt = 0; nt < 2; ++nt)
          acc[mt][nt] = mfma16(av[mt], bv[nt], acc[mt][nt]);
    }
  }
  #pragma unroll
  for (int mt = 0; mt < 4; ++mt) {
    #pragma unroll
    for (int nt = 0; nt < 2; ++nt) {
      #pragma unroll
      for (int r = 0; r < 4; ++r) {
        int gr = bm + wr * 64 + mt * 16 + g * 4 + r;
        int gc = bn + wc * 32 + nt * 16 + li;
        float v = acc[mt][nt][r] + bias[gc];
        if (EPI == 0) C0[(size_t)gr * ldc + gc] = v;
        else          C0[(size_t)gr * ldc + gc] = fmaxf(v, 0.f) + resid[(size_t)gr * 768 + gc];
      }
    }
  }
}

// ---------------- edge aggregation (CSR gather-sum, bf16 Y, u32x2 vectorized) ----------------
// 192 threads/block; thread t owns 4 bf16 columns [4t..4t+3]
__global__ void agg_kernel(const u16* __restrict__ Y, const int* __restrict__ offs,
                           const int* __restrict__ pack, u16* __restrict__ Aupd) {
  const int v = blockIdx.x, t = threadIdx.x;
  float a0 = 0.f, a1 = 0.f, a2 = 0.f, a3 = 0.f;
  const int beg = offs[v], end = offs[v + 1];
  const u32* Yw = (const u32*)Y;
  for (int i = beg; i < end; ++i) {
    int p = pack[i];                     // p = src | (etype<<12) => (etype*4096+src) = p
    u32x2 w = *(const u32x2*)(Yw + (size_t)p * 384 + t * 2);
    a0 += bf2f((u16)(w.x & 0xffffu));
    a1 += bf2f((u16)(w.x >> 16));
    a2 += bf2f((u16)(w.y & 0xffffu));
    a3 += bf2f((u16)(w.y >> 16));
  }
  u32x2 o;
  o.x = (u32)f2bf(a0) | ((u32)f2bf(a1) << 16);
  o.y = (u32)f2bf(a2) | ((u32)f2bf(a3) << 16);
  *(u32x2*)((u32*)(Aupd + (size_t)v * 1536 + 768) + t * 2) = o;
}

// ---------------- layernorm + bf16 pack ----------------
__global__ void ln_kernel(const float* __restrict__ xin, const float* __restrict__ gam,
                          const float* __restrict__ bet,
                          float* __restrict__ x, u16* __restrict__ Amsg, u16* __restrict__ Aupd,
                          float* __restrict__ xcopy) {
  __shared__ float red[256];
  int v = blockIdx.x, t = threadIdx.x;
  const float* r = xin + (size_t)v * 768;
  float v0 = r[t], v1 = r[t + 256], v2 = r[t + 512];
  red[t] = v0 + v1 + v2;
  __syncthreads();
  for (int off = 128; off > 0; off >>= 1) { if (t < off) red[t] += red[t + off]; __syncthreads(); }
  float mu = red[0] * (1.f / 768.f);
  __syncthreads();
  float d0 = v0 - mu, d1 = v1 - mu, d2 = v2 - mu;
  red[t] = d0 * d0 + d1 * d1 + d2 * d2;
  __syncthreads();
  for (int off = 128; off > 0; off >>= 1) { if (t < off) red[t] += red[t + off]; __syncthreads(); }
  float rstd = rsqrtf(red[0] * (1.f / 768.f) + 1e-5f);
  float dv[3] = {d0, d1, d2};
  #pragma unroll
  for (int i = 0; i < 3; ++i) {
    int c = t + i * 256;
    float y = gam[c] * dv[i] * rstd + bet[c];
    x[(size_t)v * 768 + c] = y;
    if (xcopy) xcopy[(size_t)v * 768 + c] = y;
    u16 hi = f2bf(y);
    Amsg[(size_t)v * 768 + c] = hi;
    Aupd[(size_t)v * 1536 + c] = hi;
  }
}

// ---------------- flash attention, split-K, 32q/wave, chunked XCD swizzle ----------------
__global__ void __launch_bounds__(256, 3)
flash_kernel(const u16* __restrict__ Qb, const u16* __restrict__ Kb,
             const u16* __restrict__ Vtb, u16* __restrict__ Opb,
             float* __restrict__ Mp, float* __restrict__ Lp) {
  __shared__ alignas(16) u16 sK[6144];      // chunked [kc][g][krow64][8]
  __shared__ alignas(16) u16 sV[6144];      // V^T [96 d][64 k], XOR-swizzled
  __shared__ alignas(16) u16 sP[4][2048];   // per-wave [32 q][64 k], XOR-swizzled
  const int tid = threadIdx.x, lane = tid & 63, wid = tid >> 6;
  const int li = lane & 15, g = lane >> 4;
  // chunked XCD remap: XCD c gets L in [128c,128c+128) = all 32 qt x 4 h x 1 kcb
  const int R = blockIdx.x + 32 * (blockIdx.y + 8 * blockIdx.z);
  const int L = (R & 7) * 128 + (R >> 3);
  const int qt = L & 31, h = (L >> 5) & 7, kcb = L >> 8;
  const int vrow = tid >> 3, vcol = (tid & 7) ^ (vrow & 7);

  const u16* Qg = Qb + ((size_t)(h << 12) + qt * 128 + wid * 32 + li) * 96 + g * 8;
  bf16x8 aq0[3], aq1[3];
  #pragma unroll
  for (int kc = 0; kc < 3; ++kc) {
    aq0[kc] = *(const bf16x8*)(Qg + kc * 32);
    aq1[kc] = *(const bf16x8*)(Qg + 1536 + kc * 32);
  }

  float m0 = -1e30f, l0 = 0.f, m1 = -1e30f, l1 = 0.f;
  const f32x4 vz = {0.f, 0.f, 0.f, 0.f};
  f32x4 o0[6], o1[6];
  #pragma unroll
  for (int dt = 0; dt < 6; ++dt) { o0[dt] = vz; o1[dt] = vz; }

  const char* Kg = (const char*)(Kb + (size_t)(h << 12) * 96);
  const char* Vg = (const char*)(Vtb + (size_t)h * 96 * 4096);
  char* sKb = (char*)sK; char* sVb = (char*)sV; char* sPb = (char*)sP[wid];

  for (int kt = kcb * 16; kt < kcb * 16 + 16; ++kt) {
    __syncthreads();
    #pragma unroll
    for (int j = 0; j < 3; ++j) {
      gl_lds16(Kg + ((size_t)(kt * 64 + lane) * 96 + j * 32 + wid * 8) * 2, sKb + j * 4096 + wid * 1024);
      gl_lds16(Vg + (size_t)(j * 32 + vrow) * 8192 + kt * 128 + vcol * 16, sVb + j * 4096 + wid * 1024);
    }
    __syncthreads();

    // S^T = K·Q^T for both q-frags; K fragments read once, used twice
    f32x4 s0[4], s1[4];
    __builtin_amdgcn_s_setprio(1);
    #pragma unroll
    for (int nt = 0; nt < 4; ++nt) {
      s0[nt] = vz; s1[nt] = vz;
      #pragma unroll
      for (int kc = 0; kc < 3; ++kc) {
        bf16x8 bk = *(const bf16x8*)(sKb + kc * 4096 + g * 1024 + (nt * 16 + li) * 16);
        s0[nt] = mfma16(bk, aq0[kc], s0[nt]);
        s1[nt] = mfma16(bk, aq1[kc], s1[nt]);
      }
    }
    __builtin_amdgcn_s_setprio(0);

    // softmax qf0 (lane-local q = wid*32 + li, replicated over g)
    {
      float mx = fmaxf(fmaxf(fmaxf(s0[0][0], s0[0][1]), fmaxf(s0[0][2], s0[0][3])),
                       fmaxf(fmaxf(s0[1][0], s0[1][1]), fmaxf(s0[1][2], s0[1][3])));
      mx = fmaxf(mx, fmaxf(fmaxf(fmaxf(s0[2][0], s0[2][1]), fmaxf(s0[2][2], s0[2][3])),
                           fmaxf(fmaxf(s0[3][0], s0[3][1]), fmaxf(s0[3][2], s0[3][3]))));
      mx = fmaxf(mx, __shfl_xor(mx, 16));
      mx = fmaxf(mx, __shfl_xor(mx, 32));
      float mnew = fmaxf(m0, mx);
      float alpha = __expf(m0 - mnew);
      float rs = 0.f;
      #pragma unroll
      for (int nt = 0; nt < 4; ++nt)
        #pragma unroll
        for (int r = 0; r < 4; ++r) { float p = __expf(s0[nt][r] - mnew); s0[nt][r] = p; rs += p; }
      rs += __shfl_xor(rs, 16);
      rs += __shfl_xor(rs, 32);
      l0 = l0 * alpha + rs;
      m0 = mnew;
      #pragma unroll
      for (int dt = 0; dt < 6; ++dt) o0[dt] *= alpha;
      #pragma unroll
      for (int nt = 0; nt < 4; ++nt) {
        u32x2 w;
        w.x = (u32)f2bf(s0[nt][0]) | ((u32)f2bf(s0[nt][1]) << 16);
        w.y = (u32)f2bf(s0[nt][2]) | ((u32)f2bf(s0[nt][3]) << 16);
        *(u32x2*)(sPb + li * 128 + (((nt * 16 + g * 4) * 2) ^ ((li & 7) << 4))) = w;
      }
    }
    // softmax qf1
    {
      float mx = fmaxf(fmaxf(fmaxf(s1[0][0], s1[0][1]), fmaxf(s1[0][2], s1[0][3])),
                       fmaxf(fmaxf(s1[1][0], s1[1][1]), fmaxf(s1[1][2], s1[1][3])));
      mx = fmaxf(mx, fmaxf(fmaxf(fmaxf(s1[2][0], s1[2][1]), fmaxf(s1[2][2], s1[2][3])),
                           fmaxf(fmaxf(s1[3][0], s1[3][1]), fmaxf(s1[3][2], s1[3][3]))));
      mx = fmaxf(mx, __shfl_xor(mx, 16));
      mx = fmaxf(mx, __shfl_xor(mx, 32));
      float mnew = fmaxf(m1, mx);
      float alpha = __expf(m1 - mnew);
      float rs = 0.f;
      #pragma unroll
      for (int nt = 0; nt < 4; ++nt)
        #pragma unroll
        for (int r = 0; r < 4; ++r) { float p = __expf(s1[nt][r] - mnew); s1[nt][r] = p; rs += p; }
      rs += __shfl_xor(rs, 16);
      rs += __shfl_xor(rs, 32);
      l1 = l1 * alpha + rs;
      m1 = mnew;
      #pragma unroll
      for (int dt = 0; dt < 6; ++dt) o1[dt] *= alpha;
      #pragma unroll
      for (int nt = 0; nt < 4; ++nt) {
        u32x2 w;
        w.x = (u32)f2bf(s1[nt][0]) | ((u32)f2bf(s1[nt][1]) << 16);
        w.y = (u32)f2bf(s1[nt][2]) | ((u32)f2bf(s1[nt][3]) << 16);
        *(u32x2*)(sPb + (16 + li) * 128 + (((nt * 16 + g * 4) * 2) ^ ((li & 7) << 4))) = w;
      }
    }

    // PV: V fragments read once, used for both q-frags
    __builtin_amdgcn_s_setprio(1);
    #pragma unroll
    for (int kc2 = 0; kc2 < 2; ++kc2) {
      bf16x8 pa0 = *(const bf16x8*)(sPb + li * 128 + ((kc2 * 64 + g * 16) ^ ((li & 7) << 4)));
      bf16x8 pa1 = *(const bf16x8*)(sPb + (16 + li) * 128 + ((kc2 * 64 + g * 16) ^ ((li & 7) << 4)));
      #pragma unroll
      for (int dt = 0; dt < 6; ++dt) {
        int d = dt * 16 + li;
        bf16x8 bvv = *(const bf16x8*)(sVb + d * 128 + ((kc2 * 64 + g * 16) ^ ((d & 7) << 4)));
        o0[dt] = mfma16(pa0, bvv, o0[dt]);
        o1[dt] = mfma16(pa1, bvv, o1[dt]);
      }
    }
    __builtin_amdgcn_s_setprio(0);
  }
  int bq = qt * 128 + wid * 32;
  size_t cb = (size_t)(((kcb * 8 + h) << 12));
  #pragma unroll
  for (int dt = 0; dt < 6; ++dt)
    #pragma unroll
    for (int r = 0; r < 4; ++r) {
      int d = dt * 16 + li;
      Opb[(cb + bq + g * 4 + r) * 96 + d] = f2bf(o0[dt][r]);
      Opb[(cb + bq + 16 + g * 4 + r) * 96 + d] = f2bf(o1[dt][r]);
    }
  if (g == 0) {
    Mp[cb + bq + li] = m0;      Lp[cb + bq + li] = l0;
    Mp[cb + bq + 16 + li] = m1; Lp[cb + bq + 16 + li] = l1;
  }
}

// ---------------- merge split-K partials (bf16 Op) -> ctx (bf16) + stats ----------------
__global__ void merge_kernel(const u16* __restrict__ Opb, const float* __restrict__ Mp,
                             const float* __restrict__ Lp,
                             u16* __restrict__ ctxb, float* __restrict__ stats) {
  int row = blockIdx.x, t = threadIdx.x;
  #pragma unroll
  for (int i = 0; i < 3; ++i) {
    int idx = t + i * 256;
    int h = idx / 96, d = idx - h * 96;
    int base = (h << 12) + row;
    float m0 = Mp[base], m1 = Mp[32768 + base], m2 = Mp[65536 + base], m3 = Mp[98304 + base];
    float M = fmaxf(fmaxf(m0, m1), fmaxf(m2, m3));
    float w0 = __expf(m0 - M), w1 = __expf(m1 - M), w2 = __expf(m2 - M), w3 = __expf(m3 - M);
    float L = w0 * Lp[base] + w1 * Lp[32768 + base] + w2 * Lp[65536 + base] + w3 * Lp[98304 + base];
    float o = w0 * bf2f(Opb[(size_t)base * 96 + d])
            + w1 * bf2f(Opb[(size_t)(32768 + base) * 96 + d])
            + w2 * bf2f(Opb[(size_t)(65536 + base) * 96 + d])
            + w3 * bf2f(Opb[(size_t)(98304 + base) * 96 + d]);
    float invl = 1.f / L;
    ctxb[(size_t)row * 768 + idx] = f2bf(o * invl);
    if (d == 0) {
      stats[base] = M;
      stats[32768 + base] = invl;
    }
  }
}

// ---------------- head-averaged attention weights, 32q/wave, chunked XCD swizzle ----------------
__global__ void __launch_bounds__(256, 3)
mean_kernel(const u16* __restrict__ Qb, const u16* __restrict__ Kb,
            const float* __restrict__ stats, float* __restrict__ out) {
  __shared__ alignas(16) u16 sQ[12288];   // [kc3][g4][row128][8]
  __shared__ alignas(16) u16 sK2[6144];   // [kc3][g4][row64][8]
  const int tid = threadIdx.x, lane = tid & 63, wid = tid >> 6;
  const int li = lane & 15, g = lane >> 4;
  // chunked XCD remap: XCD c gets L in [256c,256c+256) = all 32 q-tiles x 8 k-tiles
  const int R = blockIdx.x + 32 * blockIdx.y;
  const int L = (R & 7) * 256 + (R >> 3);
  const int q0 = (L & 31) * 128, k0 = (L >> 5) * 64;
  const f32x4 vz = {0.f, 0.f, 0.f, 0.f};
  f32x4 macc0[4], macc1[4];
  #pragma unroll
  for (int nt = 0; nt < 4; ++nt) { macc0[nt] = vz; macc1[nt] = vz; }
  char* sQb = (char*)sQ; char* sKb = (char*)sK2;
  const int rq = (wid & 1) * 64 + lane;   // Q staging row
  const int ccb = wid >> 1;

  for (int h = 0; h < 8; ++h) {
    __syncthreads();
    #pragma unroll
    for (int i = 0; i < 6; ++i) {
      int cc = i * 2 + ccb, kc = cc >> 2, gg = cc & 3;
      gl_lds16((const char*)Qb + ((size_t)(h << 12) + q0 + rq) * 192 + kc * 64 + gg * 16,
               sQb + kc * 8192 + gg * 2048 + (wid & 1) * 1024);
    }
    #pragma unroll
    for (int i = 0; i < 3; ++i) {
      int c = i * 4 + wid, kc = c >> 2, gg = c & 3;
      gl_lds16((const char*)Kb + ((size_t)(h << 12) + k0 + lane) * 192 + kc * 64 + gg * 16,
               sKb + kc * 4096 + gg * 1024);
    }
    __syncthreads();

    bf16x8 a20[3], a21[3];
    #pragma unroll
    for (int kc = 0; kc < 3; ++kc) {
      a20[kc] = *(const bf16x8*)(sQb + kc * 8192 + g * 2048 + (wid * 32 + li) * 16);
      a21[kc] = *(const bf16x8*)(sQb + kc * 8192 + g * 2048 + (wid * 32 + 16 + li) * 16);
    }
    f32x4 s0[4], s1[4];
    __builtin_amdgcn_s_setprio(1);
    #pragma unroll
    for (int nt = 0; nt < 4; ++nt) {
      s0[nt] = vz; s1[nt] = vz;
      #pragma unroll
      for (int kc = 0; kc < 3; ++kc) {
        bf16x8 bk = *(const bf16x8*)(sKb + kc * 4096 + g * 1024 + (nt * 16 + li) * 16);
        s0[nt] = mfma16(a20[kc], bk, s0[nt]);
        s1[nt] = mfma16(a21[kc], bk, s1[nt]);
      }
    }
    __builtin_amdgcn_s_setprio(0);
    #pragma unroll
    for (int r = 0; r < 4; ++r) {
      int row0 = q0 + wid * 32 + g * 4 + r;
      float mm0 = stats[(h << 12) + row0];
      float si0 = 0.125f * stats[32768 + (h << 12) + row0];
      int row1 = row0 + 16;
      float mm1 = stats[(h << 12) + row1];
      float si1 = 0.125f * stats[32768 + (h << 12) + row1];
      #pragma unroll
      for (int nt = 0; nt < 4; ++nt) {
        macc0[nt][r] += __expf(s0[nt][r] - mm0) * si0;
        macc1[nt][r] += __expf(s1[nt][r] - mm1) * si1;
      }
    }
  }
  #pragma unroll
  for (int nt = 0; nt < 4; ++nt)
    #pragma unroll
    for (int r = 0; r < 4; ++r) {
      out[(size_t)(q0 + wid * 32 + g * 4 + r) * 4096 + k0 + nt * 16 + li] = macc0[nt][r];
      out[(size_t)(q0 + wid * 32 + 16 + g * 4 + r) * 4096 + k0 + nt * 16 + li] = macc1[nt][r];
    }
}

// ---------------- pooled mean + analyzer MLP (parallelized) ----------------
__global__ void colsum_kernel(const float* __restrict__ gr, float* __restrict__ part) {
  int b = blockIdx.x, t = threadIdx.x;   // 256 blocks x 16 rows
  float s0 = 0.f, s1 = 0.f, s2 = 0.f;
  for (int rr = 0; rr < 16; ++rr) {
    const float* row = gr + (size_t)(b * 16 + rr) * 768;
    s0 += row[t]; s1 += row[t + 256]; s2 += row[t + 512];
  }
  part[b * 768 + t] = s0; part[b * 768 + t + 256] = s1; part[b * 768 + t + 512] = s2;
}
__global__ void pool_kernel(const float* __restrict__ part, float* __restrict__ pool) {
  int t = blockIdx.x * 256 + threadIdx.x;   // grid 3x256 = 768
  float s = 0.f;
  for (int b = 0; b < 256; ++b) s += part[b * 768 + t];
  pool[t] = s * (1.f / 4096.f);
}
// one wave per output neuron
template<int KDIM>
__global__ void mlp_fc_kernel(const float* __restrict__ in, const float* __restrict__ Wm,
                              const float* __restrict__ bb, float* __restrict__ outv) {
  int o = blockIdx.x * 4 + (threadIdx.x >> 6);
  int lane = threadIdx.x & 63;
  const float* w = Wm + (size_t)o * KDIM;
  float s = 0.f;
  #pragma unroll
  for (int k = lane; k < KDIM; k += 64) s += w[k] * in[k];
  s += __shfl_xor(s, 1);  s += __shfl_xor(s, 2);  s += __shfl_xor(s, 4);
  s += __shfl_xor(s, 8);  s += __shfl_xor(s, 16); s += __shfl_xor(s, 32);
  if (lane == 0) outv[o] = fmaxf(s + bb[o], 0.f);
}
__global__ void mlp3_kernel(const float* __restrict__ h2,
                            const float* __restrict__ W3, const float* __restrict__ b3,
                            float* __restrict__ out) {
  __shared__ float red[256];
  int t = threadIdx.x;
  red[t] = W3[t] * h2[t];
  __syncthreads();
  for (int off = 128; off > 0; off >>= 1) { if (t < off) red[t] += red[t + off]; __syncthreads(); }
  if (t == 0) out[0] = 1.f / (1.f + __expf(-(red[0] + b3[0])));
}

// ---------------- host orchestration ----------------
extern "C" void kernel_launch(void* const* d_in, const int* in_sizes, int n_in,
                              void* d_out, int out_size, void* d_ws, size_t ws_size,
                              hipStream_t stream) {
  const float* nf   = (const float*)d_in[0];
  const int*   ei   = (const int*)d_in[1];
  const int*   ety  = (const int*)d_in[2];
  const int*   nty  = (const int*)d_in[3];
  const float* se   = (const float*)d_in[4];
  const float* ce   = (const float*)d_in[5];
  const float* ae   = (const float*)d_in[6];
  const float* msgW = (const float*)d_in[7];
  const float* msgb = (const float*)d_in[8];
  const float* updW = (const float*)d_in[9];
  const float* updb = (const float*)d_in[10];
  const float* lng  = (const float*)d_in[11];
  const float* lnb  = (const float*)d_in[12];
  const float* ipW  = (const float*)d_in[13];
  const float* ipb  = (const float*)d_in[14];
  const float* opW  = (const float*)d_in[15];
  const float* opb  = (const float*)d_in[16];
  const float* aW1  = (const float*)d_in[17];
  const float* ab1  = (const float*)d_in[18];
  const float* aW2  = (const float*)d_in[19];
  const float* ab2  = (const float*)d_in[20];
  const float* aW3  = (const float*)d_in[21];
  const float* ab3  = (const float*)d_in[22];

  void* wsp = nullptr;
  hipGetSymbolAddress(&wsp, HIP_SYMBOL(g_ws));
  unsigned char* W = (unsigned char*)wsp;

  float* x     = (float*)(W + OFF_X);
  float* x2    = (float*)(W + OFF_X2);
  u16* Amsg    = (u16*)(W + OFF_AMSG);
  u16* Aupd    = (u16*)(W + OFF_AUPD);
  u16* Wmsg    = (u16*)(W + OFF_WMSG);
  u16* Wupd    = (u16*)(W + OFF_WUPD);
  u16* Wip     = (u16*)(W + OFF_WIP);
  u16* Wop     = (u16*)(W + OFF_WOP);
  u16* Qb      = (u16*)(W + OFF_Q);
  u16* Kb      = (u16*)(W + OFF_K);
  u16* Vtb     = (u16*)(W + OFF_V);
  u16* Ctxb    = (u16*)(W + OFF_CTX);
  float* stats = (float*)(W + OFF_STATS);
  float* Mp    = (float*)(W + OFF_ML);
  float* Lp    = Mp + 131072;
  int* deg     = (int*)(W + OFF_DEG);
  int* offs    = (int*)(W + OFF_OFFS);
  int* cur     = (int*)(W + OFF_CUR);
  int* pack    = (int*)(W + OFF_PACK);
  float* part  = (float*)(W + OFF_PART);
  float* pool  = (float*)(W + OFF_POOL);
  float* h1b   = (float*)(W + OFF_H1);
  float* h2b   = (float*)(W + OFF_H2);
  u16*   Yb    = (u16*)(W + OFF_Y);

  float* out_x    = (float*)d_out;
  float* out_gr   = out_x + (size_t)NNODE * DMODEL;
  float* out_sc   = out_gr + (size_t)NNODE * DMODEL;
  float* out_attn = out_sc + 1;
  u16*   Opb      = (u16*)out_attn;  // flash o-partials bf16, 25 MB (overwritten by mean_kernel)

  // CSR build
  zero_kernel<<<16, 256, 0, stream>>>(deg, NNODE);
  deg_kernel<<<NEDGE / 256, 256, 0, stream>>>(ei, deg);
  scan_kernel<<<1, 1024, 0, stream>>>(deg, offs, cur);
  scatter_kernel<<<NEDGE / 256, 256, 0, stream>>>(ei, ety, cur, pack);

  // weight conversions (all layers upfront, 4 elems/thread)
  convert_bf_kernel<<<2048, 256, 0, stream>>>(msgW, Wmsg, 3 * 5 * 768 * 768 / 4);
  convert_bf_kernel<<<1024, 256, 0, stream>>>(updW, Wupd, 3 * 768 * 1536 / 4);
  convert_bf_kernel<<<1024, 256, 0, stream>>>(ipW, Wip, 2304 * 768 / 4);
  convert_bf_kernel<<<512, 256, 0, stream>>>(opW, Wop, 768 * 768 / 4);

  // x = node_features + typed embedding
  embed_kernel<<<NNODE, 256, 0, stream>>>(nf, nty, se, ce, ae, x, Amsg, Aupd);

  for (int l = 0; l < 3; ++l) {
    // Y[t] = x @ msg_W[t]^T + b[t]  (bf16 out, 5 types via grid.z; XCD-swizzled)
    gemm_bt<3><<<dim3(6, 32, 5), 256, 0, stream>>>(Amsg, 768,
        Wmsg + (size_t)l * 5 * 768 * 768, 768, 768,
        msgb + (size_t)l * 5 * 768, nullptr, 768, nullptr, Yb, nullptr, nullptr,
        (long)768 * 768, 768, (long)NNODE * DMODEL);
    agg_kernel<<<NNODE, 192, 0, stream>>>(Yb, offs, pack, Aupd);
    // x2 = relu([x|agg] @ upd_W^T + b) + x   (narrow tile: 384 blocks)
    gemm_bt64<1><<<dim3(12, 32), 256, 0, stream>>>(Aupd, 1536,
        Wupd + (size_t)l * 768 * 1536, 1536, 1536,
        updb + (size_t)l * 768, x2, 768, x);
    ln_kernel<<<NNODE, 256, 0, stream>>>(x2, lng + (size_t)l * 768, lnb + (size_t)l * 768,
        x, Amsg, Aupd, (l == 2) ? out_x : nullptr);
  }

  // attention (qkv back to 128x128 tile: lower A-staging traffic)
  gemm_bt<2><<<dim3(18, 32, 1), 256, 0, stream>>>(Amsg, 768, Wip, 768, 768,
      ipb, nullptr, 0, nullptr, Qb, Kb, Vtb, 0, 0, 0);
  flash_kernel<<<dim3(32, 8, 4), 256, 0, stream>>>(Qb, Kb, Vtb, Opb, Mp, Lp);
  merge_kernel<<<NNODE, 256, 0, stream>>>(Opb, Mp, Lp, Ctxb, stats);
  mean_kernel<<<dim3(32, 64), 256, 0, stream>>>(Qb, Kb, stats, out_attn);
  gemm_bt64<0><<<dim3(12, 32), 256, 0, stream>>>(Ctxb, 768, Wop, 768, 768,
      opb, out_gr, 768, nullptr);

  // pooled mean + MLP + sigmoid (parallelized)
  colsum_kernel<<<256, 256, 0, stream>>>(out_gr, part);
  pool_kernel<<<3, 256, 0, stream>>>(part, pool);
  mlp_fc_kernel<768><<<128, 256, 0, stream>>>(pool, aW1, ab1, h1b);
  mlp_fc_kernel<512><<<64, 256, 0, stream>>>(h1b, aW2, ab2, h2b);
  mlp3_kernel<<<1, 256, 0, stream>>>(h2b, aW3, ab3, out_sc);
}

// Round 18
// 601.053 us; speedup vs baseline: 1.0280x; 1.0280x over previous
//
#include <hip/hip_runtime.h>

typedef unsigned short u16;
typedef unsigned int u32;
typedef __attribute__((ext_vector_type(4))) float f32x4;
typedef __attribute__((ext_vector_type(8))) __bf16 bf16x8;
typedef __attribute__((ext_vector_type(4))) unsigned int u32x4;
typedef __attribute__((ext_vector_type(2))) unsigned int u32x2;

#define DEV static __device__ __forceinline__

// ---------------- problem constants ----------------
#define NNODE 4096
#define DMODEL 768
#define NEDGE 131072

// ---------------- static workspace ----------------
static constexpr size_t OFF_X     = 0;           // f32 [4096][768]
static constexpr size_t OFF_X2    = 12582912;    // f32 [4096][768] pre-LN
static constexpr size_t OFF_AMSG  = 25165824;    // bf16 [4096][768]
static constexpr size_t OFF_AUPD  = 31457280;    // bf16 [4096][1536] = [xh, aggh]
static constexpr size_t OFF_WMSG  = 44040192;    // bf16 [3][5][768][768]
static constexpr size_t OFF_WUPD  = 61734912;    // bf16 [3][768][1536]
static constexpr size_t OFF_WIP   = 68812800;    // bf16 [2304][768]
static constexpr size_t OFF_WOP   = 72351744;    // bf16 [768][768]
static constexpr size_t OFF_Q     = 73531392;    // bf16 [8][4096][96] (pre-scaled)
static constexpr size_t OFF_K     = 79822848;    // bf16 [8][4096][96]
static constexpr size_t OFF_V     = 86114304;    // bf16 [8][96][4096] (transposed)
static constexpr size_t OFF_CTX   = 92405760;    // bf16 [4096][768]
static constexpr size_t OFF_STATS = 98697216;    // f32 [2][8][4096] (m, invl)
static constexpr size_t OFF_ML    = 98959360;    // f32 [2][4][8][4096] (m,l partials)
static constexpr size_t OFF_DEG   = 100007936;   // int [4096]
static constexpr size_t OFF_OFFS  = 100024320;   // int [4097]
static constexpr size_t OFF_CUR   = 100040960;   // int [4096]
static constexpr size_t OFF_PACK  = 100057344;   // int [131072] src | etype<<12
static constexpr size_t OFF_PART  = 100581632;   // f32 [256][768]
static constexpr size_t OFF_POOL  = 101368064;   // f32 [768]
static constexpr size_t OFF_H1    = 101371136;   // f32 [512]
static constexpr size_t OFF_H2    = 101373184;   // f32 [256]
static constexpr size_t OFF_Y     = 101374208;   // bf16 [5][4096][768] (8B-aligned)
static constexpr size_t WS_TOTAL  = 132831488;

__device__ __attribute__((aligned(256))) unsigned char g_ws[WS_TOTAL];

// ---------------- helpers ----------------
DEV u16 f2bf(float f) {                       // native v_cvt (RTNE)
  return __builtin_bit_cast(u16, (__bf16)f);
}
DEV float bf2f(u16 h) {
  union { unsigned u; float f; } v; v.u = ((unsigned)h) << 16;
  return v.f;
}
DEV void gl_lds16(const void* g, void* l) {
  __builtin_amdgcn_global_load_lds((const __attribute__((address_space(1))) void*)g,
                                   (__attribute__((address_space(3))) void*)l, 16, 0, 0);
}
DEV f32x4 mfma16(bf16x8 a, bf16x8 b, f32x4 c) {
  return __builtin_amdgcn_mfma_f32_16x16x32_bf16(a, b, c, 0, 0, 0);
}
// bijective XCD swizzle: rank order (z, bm, bn), bn fastest.
// requires nwg % 8 == 0 (all call sites satisfy this).
DEV void xcd_swz(int& z, int& bmy, int& bnx) {
  const int gx = gridDim.x, gy = gridDim.y;
  const int nwg = gx * gy * gridDim.z;
  const int L = blockIdx.x + gx * (blockIdx.y + gy * blockIdx.z);
  const int R = (L & 7) * (nwg >> 3) + (L >> 3);
  const int gxy = gx * gy;
  z = R / gxy;
  const int rem = R - z * gxy;
  bmy = rem / gx;
  bnx = rem - bmy * gx;
}

// ---------------- CSR build ----------------
__global__ void zero_kernel(int* p, int n) {
  int i = blockIdx.x * 256 + threadIdx.x;
  if (i < n) p[i] = 0;
}
__global__ void deg_kernel(const int* __restrict__ ei, int* __restrict__ deg) {
  int e = blockIdx.x * 256 + threadIdx.x;
  atomicAdd(&deg[ei[NEDGE + e]], 1);
}
__global__ void scan_kernel(const int* __restrict__ deg, int* __restrict__ offs, int* __restrict__ cur) {
  __shared__ int buf[1024];
  int t = threadIdx.x;
  int v0 = deg[t*4], v1 = deg[t*4+1], v2 = deg[t*4+2], v3 = deg[t*4+3];
  int s = v0 + v1 + v2 + v3;
  buf[t] = s;
  __syncthreads();
  for (int off = 1; off < 1024; off <<= 1) {
    int add = (t >= off) ? buf[t - off] : 0;
    __syncthreads();
    buf[t] += add;
    __syncthreads();
  }
  int run = buf[t] - s;
  offs[t*4] = run; cur[t*4] = run; run += v0;
  offs[t*4+1] = run; cur[t*4+1] = run; run += v1;
  offs[t*4+2] = run; cur[t*4+2] = run; run += v2;
  offs[t*4+3] = run; cur[t*4+3] = run; run += v3;
  if (t == 1023) offs[4096] = run;
}
__global__ void scatter_kernel(const int* __restrict__ ei, const int* __restrict__ ety,
                               int* __restrict__ cur, int* __restrict__ pack) {
  int e = blockIdx.x * 256 + threadIdx.x;
  int tg = ei[NEDGE + e];
  int pos = atomicAdd(&cur[tg], 1);
  pack[pos] = ei[e] | (ety[e] << 12);
}

// ---------------- weight conversion (vectorized: 4 elems/thread) ----------------
__global__ void convert_bf_kernel(const float* __restrict__ W, u16* __restrict__ out, int total4) {
  for (int i = blockIdx.x * 256 + threadIdx.x; i < total4; i += gridDim.x * 256) {
    f32x4 w = *(const f32x4*)(W + (size_t)i * 4);
    u32x2 o;
    o.x = (u32)f2bf(w.x) | ((u32)f2bf(w.y) << 16);
    o.y = (u32)f2bf(w.z) | ((u32)f2bf(w.w) << 16);
    *(u32x2*)(out + (size_t)i * 4) = o;
  }
}

// ---------------- embed + bf16 pack ----------------
__global__ void embed_kernel(const float* __restrict__ nf, const int* __restrict__ nty,
                             const float* __restrict__ se, const float* __restrict__ ce,
                             const float* __restrict__ ae,
                             float* __restrict__ x, u16* __restrict__ Amsg, u16* __restrict__ Aupd) {
  int v = blockIdx.x, t = threadIdx.x;
  int typ = nty[v];
  const float* tab = (typ == 0) ? se + (size_t)(v % 1000) * 768
                   : (typ == 1) ? ce + (size_t)(v % 5000) * 768
                                : ae + (size_t)(v % 2000) * 768;
  #pragma unroll
  for (int i = 0; i < 3; ++i) {
    int c = t + i * 256;
    float f = nf[(size_t)v * 768 + c] + tab[c];
    x[(size_t)v * 768 + c] = f;
    u16 hi = f2bf(f);
    Amsg[(size_t)v * 768 + c] = hi;
    Aupd[(size_t)v * 1536 + c] = hi;
  }
}

// ---------------- bt-GEMM 128x128: C[M,N] = A[M,K] * B[N,K]^T (XCD-swizzled) ----------------
// EPI 0: f32 C. EPI 1: relu+resid f32 C. EPI 2: qkv scatter. EPI 3: bf16 C (z-strided).
template<int EPI>
__global__ void __launch_bounds__(256, 3)
gemm_bt(const u16* __restrict__ A, int lda,
        const u16* __restrict__ B0, int ldb, int K,
        const float* __restrict__ bias0,
        float* __restrict__ C0, int ldc,
        const float* __restrict__ resid,
        u16* __restrict__ oq, u16* __restrict__ okk, u16* __restrict__ ov,
        long zsB, int zsBias, long zsC)
{
  __shared__ alignas(16) u16 sA[8192];  // [128][64] bf16, XOR-swizzled rows
  __shared__ alignas(16) u16 sB[8192];
  const int tid = threadIdx.x;
  const int lane = tid & 63, wid = tid >> 6;
  const int wr = wid >> 1, wc = wid & 1;
  const int li = lane & 15, g = lane >> 4;
  int z, bmy, bnx;
  xcd_swz(z, bmy, bnx);
  const int bm = bmy * 128, bn = bnx * 128;
  const u16* B = B0 + (size_t)z * zsB;
  const float* bias = bias0 + (size_t)z * zsBias;

  const int srow = tid >> 3;                       // 0..31
  const int scol = ((tid & 7) ^ (srow & 7)) * 8;   // pre-swizzled source col group
  const u16* Ag = A + (size_t)(bm + srow) * lda + scol;
  const u16* Bg = B + (size_t)(bn + srow) * ldb + scol;
  char* sAw = (char*)sA + wid * 1024;
  char* sBw = (char*)sB + wid * 1024;

  f32x4 acc[4][4];
  const f32x4 vz = {0.f, 0.f, 0.f, 0.f};
  #pragma unroll
  for (int i = 0; i < 4; ++i)
    #pragma unroll
    for (int j = 0; j < 4; ++j) acc[i][j] = vz;

  for (int k0 = 0; k0 < K; k0 += 64) {
    __syncthreads();
    #pragma unroll
    for (int is = 0; is < 4; ++is) {
      gl_lds16(Ag + (size_t)is * 32 * lda + k0, sAw + is * 4096);
      gl_lds16(Bg + (size_t)is * 32 * ldb + k0, sBw + is * 4096);
    }
    __syncthreads();
    #pragma unroll
    for (int kc = 0; kc < 2; ++kc) {
      bf16x8 av[4], bv[4];
      #pragma unroll
      for (int mt = 0; mt < 4; ++mt) {
        int row = wr * 64 + mt * 16 + li;
        av[mt] = *(const bf16x8*)((const char*)sA + row * 128 + ((kc * 64 + g * 16) ^ ((row & 7) << 4)));
      }
      #pragma unroll
      for (int nt = 0; nt < 4; ++nt) {
        int row = wc * 64 + nt * 16 + li;
        bv[nt] = *(const bf16x8*)((const char*)sB + row * 128 + ((kc * 64 + g * 16) ^ ((row & 7) << 4)));
      }
      #pragma unroll
      for (int mt = 0; mt < 4; ++mt)
        #pragma unroll
        for (int nt = 0; nt < 4; ++nt)
          acc[mt][nt] = mfma16(av[mt], bv[nt], acc[mt][nt]);
    }
  }
  // epilogue: C row = (lane>>4)*4+reg, col = lane&15
  #pragma unroll
  for (int mt = 0; mt < 4; ++mt) {
    #pragma unroll
    for (int nt = 0; nt < 4; ++nt) {
      #pragma unroll
      for (int r = 0; r < 4; ++r) {
        int gr = bm + wr * 64 + mt * 16 + g * 4 + r;
        int gc = bn + wc * 64 + nt * 16 + li;
        float v = acc[mt][nt][r] + bias[gc];
        if (EPI == 0) {
          C0[(size_t)z * zsC + (size_t)gr * ldc + gc] = v;
        } else if (EPI == 1) {
          C0[(size_t)gr * ldc + gc] = fmaxf(v, 0.f) + resid[(size_t)gr * 768 + gc];
        } else if (EPI == 3) {
          oq[(size_t)z * zsC + (size_t)gr * ldc + gc] = f2bf(v);
        } else {
          int part = gc / 768;
          int j = gc - part * 768;
          int h = j / 96, d = j - h * 96;
          if (part == 0)      oq[((size_t)(h << 12) + gr) * 96 + d] = f2bf(v * 0.10206207261596575f);
          else if (part == 1) okk[((size_t)(h << 12) + gr) * 96 + d] = f2bf(v);
          else                ov[((size_t)h * 96 + d) * 4096 + gr] = f2bf(v);
        }
      }
    }
  }
}

// ---------------- bt-GEMM 128x64 (narrow N; XCD-swizzled) ----------------
// EPI 0: f32 C. EPI 1: relu+resid f32 C.
template<int EPI>
__global__ void __launch_bounds__(256, 3)
gemm_bt64(const u16* __restrict__ A, int lda,
          const u16* __restrict__ B0, int ldb, int K,
          const float* __restrict__ bias,
          float* __restrict__ C0, int ldc,
          const float* __restrict__ resid)
{
  __shared__ alignas(16) u16 sA[8192];  // [128][64]
  __shared__ alignas(16) u16 sB[4096];  // [64][64]
  const int tid = threadIdx.x;
  const int lane = tid & 63, wid = tid >> 6;
  const int wr = wid >> 1, wc = wid & 1;
  const int li = lane & 15, g = lane >> 4;
  int z, bmy, bnx;
  xcd_swz(z, bmy, bnx);
  const int bm = bmy * 128, bn = bnx * 64;

  const int srow = tid >> 3;
  const int scol = ((tid & 7) ^ (srow & 7)) * 8;
  const u16* Ag = A + (size_t)(bm + srow) * lda + scol;
  const u16* Bg = B0 + (size_t)(bn + srow) * ldb + scol;
  char* sAw = (char*)sA + wid * 1024;
  char* sBw = (char*)sB + wid * 1024;

  f32x4 acc[4][2];
  const f32x4 vz = {0.f, 0.f, 0.f, 0.f};
  #pragma unroll
  for (int i = 0; i < 4; ++i) { acc[i][0] = vz; acc[i][1] = vz; }

  for (int k0 = 0; k0 < K; k0 += 64) {
    __syncthreads();
    #pragma unroll
    for (int is = 0; is < 4; ++is)
      gl_lds16(Ag + (size_t)is * 32 * lda + k0, sAw + is * 4096);
    #pragma unroll
    for (int is = 0; is < 2; ++is)
      gl_lds16(Bg + (size_t)is * 32 * ldb + k0, sBw + is * 4096);
    __syncthreads();
    #pragma unroll
    for (int kc = 0; kc < 2; ++kc) {
      bf16x8 av[4], bv[2];
      #pragma unroll
      for (int mt = 0; mt < 4; ++mt) {
        int row = wr * 64 + mt * 16 + li;
        av[mt] = *(const bf16x8*)((const char*)sA + row * 128 + ((kc * 64 + g * 16) ^ ((row & 7) << 4)));
      }
      #pragma unroll
      for (int nt = 0; nt < 2; ++nt) {
        int row = wc * 32 + nt * 16 + li;
        bv[nt] = *(const bf16x8*)((const char*)sB + row * 128 + ((kc * 64 + g * 16) ^ ((row & 7) << 4)));
      }
      #pragma unroll
      for (int mt = 0; mt < 4; ++mt)
        #pragma unroll
        for (int nt = 0; nt < 2; ++nt)
          acc[mt][nt] = mfma16(av[mt], bv[nt], acc[mt][nt]);
    }
  }
  #pragma unroll
  for (int mt = 0; mt < 4; ++mt) {
    #pragma unroll
    for (int nt = 0; nt < 2; ++nt) {
      #pragma unroll
      for (int r = 0; r < 4; ++r) {
        int gr = bm + wr * 64 + mt * 16 + g * 4 + r;
        int gc = bn + wc * 32 + nt * 16 + li;
        float v = acc[mt][nt][r] + bias[gc];
        if (EPI == 0) C0[(size_t)gr * ldc + gc] = v;
        else          C0[(size_t)gr * ldc + gc] = fmaxf(v, 0.f) + resid[(size_t)gr * 768 + gc];
      }
    }
  }
}

// ---------------- edge aggregation (CSR gather-sum, bf16 Y, u32x2 vectorized) ----------------
// 192 threads/block; thread t owns 4 bf16 columns [4t..4t+3]
__global__ void agg_kernel(const u16* __restrict__ Y, const int* __restrict__ offs,
                           const int* __restrict__ pack, u16* __restrict__ Aupd) {
  const int v = blockIdx.x, t = threadIdx.x;
  float a0 = 0.f, a1 = 0.f, a2 = 0.f, a3 = 0.f;
  const int beg = offs[v], end = offs[v + 1];
  const u32* Yw = (const u32*)Y;
  for (int i = beg; i < end; ++i) {
    int p = pack[i];                     // p = src | (etype<<12) => (etype*4096+src) = p
    u32x2 w = *(const u32x2*)(Yw + (size_t)p * 384 + t * 2);
    a0 += bf2f((u16)(w.x & 0xffffu));
    a1 += bf2f((u16)(w.x >> 16));
    a2 += bf2f((u16)(w.y & 0xffffu));
    a3 += bf2f((u16)(w.y >> 16));
  }
  u32x2 o;
  o.x = (u32)f2bf(a0) | ((u32)f2bf(a1) << 16);
  o.y = (u32)f2bf(a2) | ((u32)f2bf(a3) << 16);
  *(u32x2*)((u32*)(Aupd + (size_t)v * 1536 + 768) + t * 2) = o;
}

// ---------------- layernorm + bf16 pack ----------------
__global__ void ln_kernel(const float* __restrict__ xin, const float* __restrict__ gam,
                          const float* __restrict__ bet,
                          float* __restrict__ x, u16* __restrict__ Amsg, u16* __restrict__ Aupd,
                          float* __restrict__ xcopy) {
  __shared__ float red[256];
  int v = blockIdx.x, t = threadIdx.x;
  const float* r = xin + (size_t)v * 768;
  float v0 = r[t], v1 = r[t + 256], v2 = r[t + 512];
  red[t] = v0 + v1 + v2;
  __syncthreads();
  for (int off = 128; off > 0; off >>= 1) { if (t < off) red[t] += red[t + off]; __syncthreads(); }
  float mu = red[0] * (1.f / 768.f);
  __syncthreads();
  float d0 = v0 - mu, d1 = v1 - mu, d2 = v2 - mu;
  red[t] = d0 * d0 + d1 * d1 + d2 * d2;
  __syncthreads();
  for (int off = 128; off > 0; off >>= 1) { if (t < off) red[t] += red[t + off]; __syncthreads(); }
  float rstd = rsqrtf(red[0] * (1.f / 768.f) + 1e-5f);
  float dv[3] = {d0, d1, d2};
  #pragma unroll
  for (int i = 0; i < 3; ++i) {
    int c = t + i * 256;
    float y = gam[c] * dv[i] * rstd + bet[c];
    x[(size_t)v * 768 + c] = y;
    if (xcopy) xcopy[(size_t)v * 768 + c] = y;
    u16 hi = f2bf(y);
    Amsg[(size_t)v * 768 + c] = hi;
    Aupd[(size_t)v * 1536 + c] = hi;
  }
}

// ---------------- flash attention, split-K, 32q/wave, chunked XCD swizzle ----------------
__global__ void __launch_bounds__(256, 3)
flash_kernel(const u16* __restrict__ Qb, const u16* __restrict__ Kb,
             const u16* __restrict__ Vtb, u16* __restrict__ Opb,
             float* __restrict__ Mp, float* __restrict__ Lp) {
  __shared__ alignas(16) u16 sK[6144];      // chunked [kc][g][krow64][8]
  __shared__ alignas(16) u16 sV[6144];      // V^T [96 d][64 k], XOR-swizzled
  __shared__ alignas(16) u16 sP[4][2048];   // per-wave [32 q][64 k], XOR-swizzled
  const int tid = threadIdx.x, lane = tid & 63, wid = tid >> 6;
  const int li = lane & 15, g = lane >> 4;
  // chunked XCD remap: XCD c gets L in [128c,128c+128) = all 32 qt x 4 h x 1 kcb
  const int R = blockIdx.x + 32 * (blockIdx.y + 8 * blockIdx.z);
  const int L = (R & 7) * 128 + (R >> 3);
  const int qt = L & 31, h = (L >> 5) & 7, kcb = L >> 8;
  const int vrow = tid >> 3, vcol = (tid & 7) ^ (vrow & 7);

  const u16* Qg = Qb + ((size_t)(h << 12) + qt * 128 + wid * 32 + li) * 96 + g * 8;
  bf16x8 aq0[3], aq1[3];
  #pragma unroll
  for (int kc = 0; kc < 3; ++kc) {
    aq0[kc] = *(const bf16x8*)(Qg + kc * 32);
    aq1[kc] = *(const bf16x8*)(Qg + 1536 + kc * 32);
  }

  float m0 = -1e30f, l0 = 0.f, m1 = -1e30f, l1 = 0.f;
  const f32x4 vz = {0.f, 0.f, 0.f, 0.f};
  f32x4 o0[6], o1[6];
  #pragma unroll
  for (int dt = 0; dt < 6; ++dt) { o0[dt] = vz; o1[dt] = vz; }

  const char* Kg = (const char*)(Kb + (size_t)(h << 12) * 96);
  const char* Vg = (const char*)(Vtb + (size_t)h * 96 * 4096);
  char* sKb = (char*)sK; char* sVb = (char*)sV; char* sPb = (char*)sP[wid];

  for (int kt = kcb * 16; kt < kcb * 16 + 16; ++kt) {
    __syncthreads();
    #pragma unroll
    for (int j = 0; j < 3; ++j) {
      gl_lds16(Kg + ((size_t)(kt * 64 + lane) * 96 + j * 32 + wid * 8) * 2, sKb + j * 4096 + wid * 1024);
      gl_lds16(Vg + (size_t)(j * 32 + vrow) * 8192 + kt * 128 + vcol * 16, sVb + j * 4096 + wid * 1024);
    }
    __syncthreads();

    // S^T = K·Q^T for both q-frags; K fragments read once, used twice
    f32x4 s0[4], s1[4];
    __builtin_amdgcn_s_setprio(1);
    #pragma unroll
    for (int nt = 0; nt < 4; ++nt) {
      s0[nt] = vz; s1[nt] = vz;
      #pragma unroll
      for (int kc = 0; kc < 3; ++kc) {
        bf16x8 bk = *(const bf16x8*)(sKb + kc * 4096 + g * 1024 + (nt * 16 + li) * 16);
        s0[nt] = mfma16(bk, aq0[kc], s0[nt]);
        s1[nt] = mfma16(bk, aq1[kc], s1[nt]);
      }
    }
    __builtin_amdgcn_s_setprio(0);

    // softmax qf0 (lane-local q = wid*32 + li, replicated over g)
    {
      float mx = fmaxf(fmaxf(fmaxf(s0[0][0], s0[0][1]), fmaxf(s0[0][2], s0[0][3])),
                       fmaxf(fmaxf(s0[1][0], s0[1][1]), fmaxf(s0[1][2], s0[1][3])));
      mx = fmaxf(mx, fmaxf(fmaxf(fmaxf(s0[2][0], s0[2][1]), fmaxf(s0[2][2], s0[2][3])),
                           fmaxf(fmaxf(s0[3][0], s0[3][1]), fmaxf(s0[3][2], s0[3][3]))));
      mx = fmaxf(mx, __shfl_xor(mx, 16));
      mx = fmaxf(mx, __shfl_xor(mx, 32));
      float mnew = fmaxf(m0, mx);
      float alpha = __expf(m0 - mnew);
      float rs = 0.f;
      #pragma unroll
      for (int nt = 0; nt < 4; ++nt)
        #pragma unroll
        for (int r = 0; r < 4; ++r) { float p = __expf(s0[nt][r] - mnew); s0[nt][r] = p; rs += p; }
      rs += __shfl_xor(rs, 16);
      rs += __shfl_xor(rs, 32);
      l0 = l0 * alpha + rs;
      m0 = mnew;
      #pragma unroll
      for (int dt = 0; dt < 6; ++dt) o0[dt] *= alpha;
      #pragma unroll
      for (int nt = 0; nt < 4; ++nt) {
        u32x2 w;
        w.x = (u32)f2bf(s0[nt][0]) | ((u32)f2bf(s0[nt][1]) << 16);
        w.y = (u32)f2bf(s0[nt][2]) | ((u32)f2bf(s0[nt][3]) << 16);
        *(u32x2*)(sPb + li * 128 + (((nt * 16 + g * 4) * 2) ^ ((li & 7) << 4))) = w;
      }
    }
    // softmax qf1
    {
      float mx = fmaxf(fmaxf(fmaxf(s1[0][0], s1[0][1]), fmaxf(s1[0][2], s1[0][3])),
                       fmaxf(fmaxf(s1[1][0], s1[1][1]), fmaxf(s1[1][2], s1[1][3])));
      mx = fmaxf(mx, fmaxf(fmaxf(fmaxf(s1[2][0], s1[2][1]), fmaxf(s1[2][2], s1[2][3])),
                           fmaxf(fmaxf(s1[3][0], s1[3][1]), fmaxf(s1[3][2], s1[3][3]))));
      mx = fmaxf(mx, __shfl_xor(mx, 16));
      mx = fmaxf(mx, __shfl_xor(mx, 32));
      float mnew = fmaxf(m1, mx);
      float alpha = __expf(m1 - mnew);
      float rs = 0.f;
      #pragma unroll
      for (int nt = 0; nt < 4; ++nt)
        #pragma unroll
        for (int r = 0; r < 4; ++r) { float p = __expf(s1[nt][r] - mnew); s1[nt][r] = p; rs += p; }
      rs += __shfl_xor(rs, 16);
      rs += __shfl_xor(rs, 32);
      l1 = l1 * alpha + rs;
      m1 = mnew;
      #pragma unroll
      for (int dt = 0; dt < 6; ++dt) o1[dt] *= alpha;
      #pragma unroll
      for (int nt = 0; nt < 4; ++nt) {
        u32x2 w;
        w.x = (u32)f2bf(s1[nt][0]) | ((u32)f2bf(s1[nt][1]) << 16);
        w.y = (u32)f2bf(s1[nt][2]) | ((u32)f2bf(s1[nt][3]) << 16);
        *(u32x2*)(sPb + (16 + li) * 128 + (((nt * 16 + g * 4) * 2) ^ ((li & 7) << 4))) = w;
      }
    }

    // PV: V fragments read once, used for both q-frags
    __builtin_amdgcn_s_setprio(1);
    #pragma unroll
    for (int kc2 = 0; kc2 < 2; ++kc2) {
      bf16x8 pa0 = *(const bf16x8*)(sPb + li * 128 + ((kc2 * 64 + g * 16) ^ ((li & 7) << 4)));
      bf16x8 pa1 = *(const bf16x8*)(sPb + (16 + li) * 128 + ((kc2 * 64 + g * 16) ^ ((li & 7) << 4)));
      #pragma unroll
      for (int dt = 0; dt < 6; ++dt) {
        int d = dt * 16 + li;
        bf16x8 bvv = *(const bf16x8*)(sVb + d * 128 + ((kc2 * 64 + g * 16) ^ ((d & 7) << 4)));
        o0[dt] = mfma16(pa0, bvv, o0[dt]);
        o1[dt] = mfma16(pa1, bvv, o1[dt]);
      }
    }
    __builtin_amdgcn_s_setprio(0);
  }
  int bq = qt * 128 + wid * 32;
  size_t cb = (size_t)(((kcb * 8 + h) << 12));
  #pragma unroll
  for (int dt = 0; dt < 6; ++dt)
    #pragma unroll
    for (int r = 0; r < 4; ++r) {
      int d = dt * 16 + li;
      Opb[(cb + bq + g * 4 + r) * 96 + d] = f2bf(o0[dt][r]);
      Opb[(cb + bq + 16 + g * 4 + r) * 96 + d] = f2bf(o1[dt][r]);
    }
  if (g == 0) {
    Mp[cb + bq + li] = m0;      Lp[cb + bq + li] = l0;
    Mp[cb + bq + 16 + li] = m1; Lp[cb + bq + 16 + li] = l1;
  }
}

// ---------------- merge split-K partials (bf16 Op) -> ctx (bf16) + stats ----------------
__global__ void merge_kernel(const u16* __restrict__ Opb, const float* __restrict__ Mp,
                             const float* __restrict__ Lp,
                             u16* __restrict__ ctxb, float* __restrict__ stats) {
  int row = blockIdx.x, t = threadIdx.x;
  #pragma unroll
  for (int i = 0; i < 3; ++i) {
    int idx = t + i * 256;
    int h = idx / 96, d = idx - h * 96;
    int base = (h << 12) + row;
    float m0 = Mp[base], m1 = Mp[32768 + base], m2 = Mp[65536 + base], m3 = Mp[98304 + base];
    float M = fmaxf(fmaxf(m0, m1), fmaxf(m2, m3));
    float w0 = __expf(m0 - M), w1 = __expf(m1 - M), w2 = __expf(m2 - M), w3 = __expf(m3 - M);
    float L = w0 * Lp[base] + w1 * Lp[32768 + base] + w2 * Lp[65536 + base] + w3 * Lp[98304 + base];
    float o = w0 * bf2f(Opb[(size_t)base * 96 + d])
            + w1 * bf2f(Opb[(size_t)(32768 + base) * 96 + d])
            + w2 * bf2f(Opb[(size_t)(65536 + base) * 96 + d])
            + w3 * bf2f(Opb[(size_t)(98304 + base) * 96 + d]);
    float invl = 1.f / L;
    ctxb[(size_t)row * 768 + idx] = f2bf(o * invl);
    if (d == 0) {
      stats[base] = M;
      stats[32768 + base] = invl;
    }
  }
}

// ---------------- head-averaged attention weights, 32q/wave ----------------
__global__ void __launch_bounds__(256, 3)
mean_kernel(const u16* __restrict__ Qb, const u16* __restrict__ Kb,
            const float* __restrict__ stats, float* __restrict__ out) {
  __shared__ alignas(16) u16 sQ[12288];   // [kc3][g4][row128][8]
  __shared__ alignas(16) u16 sK2[6144];   // [kc3][g4][row64][8]
  const int tid = threadIdx.x, lane = tid & 63, wid = tid >> 6;
  const int li = lane & 15, g = lane >> 4;
  const int q0 = blockIdx.x * 128, k0 = blockIdx.y * 64;
  const f32x4 vz = {0.f, 0.f, 0.f, 0.f};
  f32x4 macc0[4], macc1[4];
  #pragma unroll
  for (int nt = 0; nt < 4; ++nt) { macc0[nt] = vz; macc1[nt] = vz; }
  char* sQb = (char*)sQ; char* sKb = (char*)sK2;
  const int rq = (wid & 1) * 64 + lane;   // Q staging row
  const int ccb = wid >> 1;

  for (int h = 0; h < 8; ++h) {
    __syncthreads();
    #pragma unroll
    for (int i = 0; i < 6; ++i) {
      int cc = i * 2 + ccb, kc = cc >> 2, gg = cc & 3;
      gl_lds16((const char*)Qb + ((size_t)(h << 12) + q0 + rq) * 192 + kc * 64 + gg * 16,
               sQb + kc * 8192 + gg * 2048 + (wid & 1) * 1024);
    }
    #pragma unroll
    for (int i = 0; i < 3; ++i) {
      int c = i * 4 + wid, kc = c >> 2, gg = c & 3;
      gl_lds16((const char*)Kb + ((size_t)(h << 12) + k0 + lane) * 192 + kc * 64 + gg * 16,
               sKb + kc * 4096 + gg * 1024);
    }
    __syncthreads();

    bf16x8 a20[3], a21[3];
    #pragma unroll
    for (int kc = 0; kc < 3; ++kc) {
      a20[kc] = *(const bf16x8*)(sQb + kc * 8192 + g * 2048 + (wid * 32 + li) * 16);
      a21[kc] = *(const bf16x8*)(sQb + kc * 8192 + g * 2048 + (wid * 32 + 16 + li) * 16);
    }
    f32x4 s0[4], s1[4];
    __builtin_amdgcn_s_setprio(1);
    #pragma unroll
    for (int nt = 0; nt < 4; ++nt) {
      s0[nt] = vz; s1[nt] = vz;
      #pragma unroll
      for (int kc = 0; kc < 3; ++kc) {
        bf16x8 bk = *(const bf16x8*)(sKb + kc * 4096 + g * 1024 + (nt * 16 + li) * 16);
        s0[nt] = mfma16(a20[kc], bk, s0[nt]);
        s1[nt] = mfma16(a21[kc], bk, s1[nt]);
      }
    }
    __builtin_amdgcn_s_setprio(0);
    #pragma unroll
    for (int r = 0; r < 4; ++r) {
      int row0 = q0 + wid * 32 + g * 4 + r;
      float mm0 = stats[(h << 12) + row0];
      float si0 = 0.125f * stats[32768 + (h << 12) + row0];
      int row1 = row0 + 16;
      float mm1 = stats[(h << 12) + row1];
      float si1 = 0.125f * stats[32768 + (h << 12) + row1];
      #pragma unroll
      for (int nt = 0; nt < 4; ++nt) {
        macc0[nt][r] += __expf(s0[nt][r] - mm0) * si0;
        macc1[nt][r] += __expf(s1[nt][r] - mm1) * si1;
      }
    }
  }
  #pragma unroll
  for (int nt = 0; nt < 4; ++nt)
    #pragma unroll
    for (int r = 0; r < 4; ++r) {
      out[(size_t)(q0 + wid * 32 + g * 4 + r) * 4096 + k0 + nt * 16 + li] = macc0[nt][r];
      out[(size_t)(q0 + wid * 32 + 16 + g * 4 + r) * 4096 + k0 + nt * 16 + li] = macc1[nt][r];
    }
}

// ---------------- pooled mean + analyzer MLP (parallelized) ----------------
__global__ void colsum_kernel(const float* __restrict__ gr, float* __restrict__ part) {
  int b = blockIdx.x, t = threadIdx.x;   // 256 blocks x 16 rows
  float s0 = 0.f, s1 = 0.f, s2 = 0.f;
  for (int rr = 0; rr < 16; ++rr) {
    const float* row = gr + (size_t)(b * 16 + rr) * 768;
    s0 += row[t]; s1 += row[t + 256]; s2 += row[t + 512];
  }
  part[b * 768 + t] = s0; part[b * 768 + t + 256] = s1; part[b * 768 + t + 512] = s2;
}
__global__ void pool_kernel(const float* __restrict__ part, float* __restrict__ pool) {
  int t = blockIdx.x * 256 + threadIdx.x;   // grid 3x256 = 768
  float s = 0.f;
  for (int b = 0; b < 256; ++b) s += part[b * 768 + t];
  pool[t] = s * (1.f / 4096.f);
}
// one wave per output neuron
template<int KDIM>
__global__ void mlp_fc_kernel(const float* __restrict__ in, const float* __restrict__ Wm,
                              const float* __restrict__ bb, float* __restrict__ outv) {
  int o = blockIdx.x * 4 + (threadIdx.x >> 6);
  int lane = threadIdx.x & 63;
  const float* w = Wm + (size_t)o * KDIM;
  float s = 0.f;
  #pragma unroll
  for (int k = lane; k < KDIM; k += 64) s += w[k] * in[k];
  s += __shfl_xor(s, 1);  s += __shfl_xor(s, 2);  s += __shfl_xor(s, 4);
  s += __shfl_xor(s, 8);  s += __shfl_xor(s, 16); s += __shfl_xor(s, 32);
  if (lane == 0) outv[o] = fmaxf(s + bb[o], 0.f);
}
__global__ void mlp3_kernel(const float* __restrict__ h2,
                            const float* __restrict__ W3, const float* __restrict__ b3,
                            float* __restrict__ out) {
  __shared__ float red[256];
  int t = threadIdx.x;
  red[t] = W3[t] * h2[t];
  __syncthreads();
  for (int off = 128; off > 0; off >>= 1) { if (t < off) red[t] += red[t + off]; __syncthreads(); }
  if (t == 0) out[0] = 1.f / (1.f + __expf(-(red[0] + b3[0])));
}

// ---------------- host orchestration ----------------
extern "C" void kernel_launch(void* const* d_in, const int* in_sizes, int n_in,
                              void* d_out, int out_size, void* d_ws, size_t ws_size,
                              hipStream_t stream) {
  const float* nf   = (const float*)d_in[0];
  const int*   ei   = (const int*)d_in[1];
  const int*   ety  = (const int*)d_in[2];
  const int*   nty  = (const int*)d_in[3];
  const float* se   = (const float*)d_in[4];
  const float* ce   = (const float*)d_in[5];
  const float* ae   = (const float*)d_in[6];
  const float* msgW = (const float*)d_in[7];
  const float* msgb = (const float*)d_in[8];
  const float* updW = (const float*)d_in[9];
  const float* updb = (const float*)d_in[10];
  const float* lng  = (const float*)d_in[11];
  const float* lnb  = (const float*)d_in[12];
  const float* ipW  = (const float*)d_in[13];
  const float* ipb  = (const float*)d_in[14];
  const float* opW  = (const float*)d_in[15];
  const float* opb  = (const float*)d_in[16];
  const float* aW1  = (const float*)d_in[17];
  const float* ab1  = (const float*)d_in[18];
  const float* aW2  = (const float*)d_in[19];
  const float* ab2  = (const float*)d_in[20];
  const float* aW3  = (const float*)d_in[21];
  const float* ab3  = (const float*)d_in[22];

  void* wsp = nullptr;
  hipGetSymbolAddress(&wsp, HIP_SYMBOL(g_ws));
  unsigned char* W = (unsigned char*)wsp;

  float* x     = (float*)(W + OFF_X);
  float* x2    = (float*)(W + OFF_X2);
  u16* Amsg    = (u16*)(W + OFF_AMSG);
  u16* Aupd    = (u16*)(W + OFF_AUPD);
  u16* Wmsg    = (u16*)(W + OFF_WMSG);
  u16* Wupd    = (u16*)(W + OFF_WUPD);
  u16* Wip     = (u16*)(W + OFF_WIP);
  u16* Wop     = (u16*)(W + OFF_WOP);
  u16* Qb      = (u16*)(W + OFF_Q);
  u16* Kb      = (u16*)(W + OFF_K);
  u16* Vtb     = (u16*)(W + OFF_V);
  u16* Ctxb    = (u16*)(W + OFF_CTX);
  float* stats = (float*)(W + OFF_STATS);
  float* Mp    = (float*)(W + OFF_ML);
  float* Lp    = Mp + 131072;
  int* deg     = (int*)(W + OFF_DEG);
  int* offs    = (int*)(W + OFF_OFFS);
  int* cur     = (int*)(W + OFF_CUR);
  int* pack    = (int*)(W + OFF_PACK);
  float* part  = (float*)(W + OFF_PART);
  float* pool  = (float*)(W + OFF_POOL);
  float* h1b   = (float*)(W + OFF_H1);
  float* h2b   = (float*)(W + OFF_H2);
  u16*   Yb    = (u16*)(W + OFF_Y);

  float* out_x    = (float*)d_out;
  float* out_gr   = out_x + (size_t)NNODE * DMODEL;
  float* out_sc   = out_gr + (size_t)NNODE * DMODEL;
  float* out_attn = out_sc + 1;
  u16*   Opb      = (u16*)out_attn;  // flash o-partials bf16, 25 MB (overwritten by mean_kernel)

  // CSR build
  zero_kernel<<<16, 256, 0, stream>>>(deg, NNODE);
  deg_kernel<<<NEDGE / 256, 256, 0, stream>>>(ei, deg);
  scan_kernel<<<1, 1024, 0, stream>>>(deg, offs, cur);
  scatter_kernel<<<NEDGE / 256, 256, 0, stream>>>(ei, ety, cur, pack);

  // weight conversions (all layers upfront, 4 elems/thread)
  convert_bf_kernel<<<2048, 256, 0, stream>>>(msgW, Wmsg, 3 * 5 * 768 * 768 / 4);
  convert_bf_kernel<<<1024, 256, 0, stream>>>(updW, Wupd, 3 * 768 * 1536 / 4);
  convert_bf_kernel<<<1024, 256, 0, stream>>>(ipW, Wip, 2304 * 768 / 4);
  convert_bf_kernel<<<512, 256, 0, stream>>>(opW, Wop, 768 * 768 / 4);

  // x = node_features + typed embedding
  embed_kernel<<<NNODE, 256, 0, stream>>>(nf, nty, se, ce, ae, x, Amsg, Aupd);

  for (int l = 0; l < 3; ++l) {
    // Y[t] = x @ msg_W[t]^T + b[t]  (bf16 out, 5 types via grid.z; XCD-swizzled)
    gemm_bt<3><<<dim3(6, 32, 5), 256, 0, stream>>>(Amsg, 768,
        Wmsg + (size_t)l * 5 * 768 * 768, 768, 768,
        msgb + (size_t)l * 5 * 768, nullptr, 768, nullptr, Yb, nullptr, nullptr,
        (long)768 * 768, 768, (long)NNODE * DMODEL);
    agg_kernel<<<NNODE, 192, 0, stream>>>(Yb, offs, pack, Aupd);
    // x2 = relu([x|agg] @ upd_W^T + b) + x   (narrow tile: 384 blocks)
    gemm_bt64<1><<<dim3(12, 32), 256, 0, stream>>>(Aupd, 1536,
        Wupd + (size_t)l * 768 * 1536, 1536, 1536,
        updb + (size_t)l * 768, x2, 768, x);
    ln_kernel<<<NNODE, 256, 0, stream>>>(x2, lng + (size_t)l * 768, lnb + (size_t)l * 768,
        x, Amsg, Aupd, (l == 2) ? out_x : nullptr);
  }

  // attention
  gemm_bt<2><<<dim3(18, 32, 1), 256, 0, stream>>>(Amsg, 768, Wip, 768, 768,
      ipb, nullptr, 0, nullptr, Qb, Kb, Vtb, 0, 0, 0);
  flash_kernel<<<dim3(32, 8, 4), 256, 0, stream>>>(Qb, Kb, Vtb, Opb, Mp, Lp);
  merge_kernel<<<NNODE, 256, 0, stream>>>(Opb, Mp, Lp, Ctxb, stats);
  mean_kernel<<<dim3(32, 64), 256, 0, stream>>>(Qb, Kb, stats, out_attn);
  gemm_bt64<0><<<dim3(12, 32), 256, 0, stream>>>(Ctxb, 768, Wop, 768, 768,
      opb, out_gr, 768, nullptr);

  // pooled mean + MLP + sigmoid (parallelized)
  colsum_kernel<<<256, 256, 0, stream>>>(out_gr, part);
  pool_kernel<<<3, 256, 0, stream>>>(part, pool);
  mlp_fc_kernel<768><<<128, 256, 0, stream>>>(pool, aW1, ab1, h1b);
  mlp_fc_kernel<512><<<64, 256, 0, stream>>>(h1b, aW2, ab2, h2b);
  mlp3_kernel<<<1, 256, 0, stream>>>(h2b, aW3, ab3, out_sc);
}